// Round 1
// baseline (904.356 us; speedup 1.0000x reference)
//
#include <hip/hip_runtime.h>
#include <hip/hip_bf16.h>
#include <math.h>

#define NUM_EMB 1024
#define DIM 256
#define N_ROWS 262144            // 8*32*32*32
#define BM 256                   // rows per block (4 waves x 64 rows)
#define NT_CODES 32              // codes per staged B tile
#define NG_ITERS (NUM_EMB / NT_CODES)
#define B_STRIDE 264             // padded bf16 stride (528 B = 33*16, 2-way bank aliasing only)

typedef __attribute__((ext_vector_type(8))) __bf16 bf16x8;
typedef __attribute__((ext_vector_type(4))) __bf16 bf16x4;
typedef __attribute__((ext_vector_type(4))) float  f32x4;

// ---------------- prep: codebook fp32 -> bf16, 0.5*||e||^2, zero counts/loss ----------------
__global__ __launch_bounds__(64) void vq_prep(const float* __restrict__ cb,
                                              __bf16* __restrict__ cb_bf,
                                              float* __restrict__ cnorms,
                                              unsigned int* __restrict__ counts,
                                              float* __restrict__ loss_sum) {
    int k = blockIdx.x, t = threadIdx.x;           // 1024 blocks x 64 threads, one code per block
    float4 v = ((const float4*)cb)[k * 64 + t];    // 64 threads x 4 floats = 256
    bf16x4 h = { (__bf16)v.x, (__bf16)v.y, (__bf16)v.z, (__bf16)v.w };
    ((bf16x4*)cb_bf)[k * 64 + t] = h;
    float ss = v.x * v.x + v.y * v.y + v.z * v.z + v.w * v.w;
    #pragma unroll
    for (int off = 32; off; off >>= 1) ss += __shfl_xor(ss, off, 64);
    if (t == 0) {
        cnorms[k] = 0.5f * ss;
        counts[k] = 0u;
        if (k == 0) loss_sum[0] = 0.f;
    }
}

// ---------------- main: fused GEMM-argmax + loss partials + histogram + gather ----------------
__global__ __launch_bounds__(256, 2) void vq_main(const float* __restrict__ in,
                                                  const float* __restrict__ cb,
                                                  const __bf16* __restrict__ cb_bf,
                                                  const float* __restrict__ cnorms,
                                                  unsigned int* __restrict__ counts,
                                                  float* __restrict__ loss_sum,
                                                  float* __restrict__ out) {
    __shared__ __bf16 Blds[2][NT_CODES * B_STRIDE];
    __shared__ float  cnlds[2][NT_CODES];
    __shared__ int    bestidx[BM];
    __shared__ float  bestscore[BM];
    __shared__ float  wsum[4], wscore[4];

    const int t    = threadIdx.x;
    const int lane = t & 63, w = t >> 6;
    const int col  = lane & 15, quad = lane >> 4;
    const int rowbase = blockIdx.x * BM + w * 64;

    // ---- A fragments: 64 rows x 256 d per wave, bf16 in registers (128 VGPRs) ----
    // A[m = lane&15][k = quad*8 + j]  (m120-verified layout), loaded direct from global fp32.
    bf16x8 afr[4][8];
    float sumsq = 0.f;
    const float4* in4 = (const float4*)in;
    #pragma unroll
    for (int mt = 0; mt < 4; mt++) {
        const float4* rp = in4 + (size_t)(rowbase + mt * 16 + col) * 64 + quad * 2;
        #pragma unroll
        for (int kk = 0; kk < 8; kk++) {
            float4 x0 = rp[kk * 8];
            float4 x1 = rp[kk * 8 + 1];
            sumsq += x0.x * x0.x + x0.y * x0.y + x0.z * x0.z + x0.w * x0.w
                   + x1.x * x1.x + x1.y * x1.y + x1.z * x1.z + x1.w * x1.w;
            bf16x8 a = { (__bf16)x0.x, (__bf16)x0.y, (__bf16)x0.z, (__bf16)x0.w,
                         (__bf16)x1.x, (__bf16)x1.y, (__bf16)x1.z, (__bf16)x1.w };
            afr[mt][kk] = a;
        }
    }

    float bs[4][4];
    int   bi[4][4];
    #pragma unroll
    for (int mt = 0; mt < 4; mt++)
        #pragma unroll
        for (int r = 0; r < 4; r++) { bs[mt][r] = -__builtin_inff(); bi[mt][r] = 0; }

    // ---- staging helper: 32 codes x 256 bf16 (+ 32 norms) into LDS buffer ----
    auto stage = [&](int ng, int buf) {
        const uint4* src = (const uint4*)(cb_bf + (size_t)ng * NT_CODES * DIM); // 32 uint4 per code row
        #pragma unroll
        for (int i = 0; i < 4; i++) {
            int c = i * 256 + t;                  // 1024 16B-chunks per tile
            int code = c >> 5, ch = c & 31;
            uint4 v = src[code * 32 + ch];
            *(uint4*)&Blds[buf][code * B_STRIDE + ch * 8] = v;   // byte off = 528*code + 16*ch, 16B aligned
        }
        if (t < NT_CODES) cnlds[buf][t] = cnorms[ng * NT_CODES + t];
    };

    stage(0, 0);
    __syncthreads();

    for (int ng = 0; ng < NG_ITERS; ng++) {
        int buf = ng & 1;
        if (ng + 1 < NG_ITERS) stage(ng + 1, buf ^ 1);

        // init acc with -0.5||e||^2 so acc = x.e - 0.5||e||^2 directly
        float cn0 = cnlds[buf][col];
        float cn1 = cnlds[buf][16 + col];
        f32x4 acc[4][2];
        #pragma unroll
        for (int mt = 0; mt < 4; mt++) {
            f32x4 z0 = { -cn0, -cn0, -cn0, -cn0 };
            f32x4 z1 = { -cn1, -cn1, -cn1, -cn1 };
            acc[mt][0] = z0;
            acc[mt][1] = z1;
        }
        #pragma unroll
        for (int kk = 0; kk < 8; kk++) {
            bf16x8 b0 = *(const bf16x8*)&Blds[buf][col * B_STRIDE + kk * 32 + quad * 8];
            bf16x8 b1 = *(const bf16x8*)&Blds[buf][(16 + col) * B_STRIDE + kk * 32 + quad * 8];
            #pragma unroll
            for (int mt = 0; mt < 4; mt++) {
                acc[mt][0] = __builtin_amdgcn_mfma_f32_16x16x32_bf16(afr[mt][kk], b0, acc[mt][0], 0, 0, 0);
                acc[mt][1] = __builtin_amdgcn_mfma_f32_16x16x32_bf16(afr[mt][kk], b1, acc[mt][1], 0, 0, 0);
            }
        }
        // running argmax update; C layout: col = lane&15 (code), row = quad*4 + reg (m89-verified)
        int cb0 = ng * NT_CODES + col, cb1 = cb0 + 16;
        #pragma unroll
        for (int mt = 0; mt < 4; mt++) {
            #pragma unroll
            for (int r = 0; r < 4; r++) {
                float s0 = acc[mt][0][r];
                if (s0 > bs[mt][r]) { bs[mt][r] = s0; bi[mt][r] = cb0; }
                float s1 = acc[mt][1][r];
                if (s1 > bs[mt][r]) { bs[mt][r] = s1; bi[mt][r] = cb1; }
            }
        }
        __syncthreads();
    }

    // ---- cross-lane argmax over the 16 col-lanes sharing each row ----
    #pragma unroll
    for (int mt = 0; mt < 4; mt++) {
        #pragma unroll
        for (int r = 0; r < 4; r++) {
            float s = bs[mt][r];
            int   i = bi[mt][r];
            #pragma unroll
            for (int off = 1; off < 16; off <<= 1) {
                float so = __shfl_xor(s, off, 64);
                int   io = __shfl_xor(i, off, 64);
                if (so > s || (so == s && io < i)) { s = so; i = io; }
            }
            if (col == 0) {
                int rl = w * 64 + mt * 16 + quad * 4 + r;
                bestidx[rl]   = i;
                bestscore[rl] = s;
            }
        }
    }

    // per-wave sum of x^2 (for loss)
    float v = sumsq;
    #pragma unroll
    for (int off = 32; off; off >>= 1) v += __shfl_xor(v, off, 64);
    if (lane == 0) wsum[w] = v;
    __syncthreads();

    // histogram: one row per thread
    atomicAdd(&counts[bestidx[t]], 1u);

    // block loss partial: sum_x2 - 2 * sum(best score)
    float sc = bestscore[t];
    #pragma unroll
    for (int off = 32; off; off >>= 1) sc += __shfl_xor(sc, off, 64);
    if (lane == 0) wscore[w] = sc;
    __syncthreads();
    if (t == 0) {
        float tot = (wsum[0] + wsum[1] + wsum[2] + wsum[3])
                  - 2.f * (wscore[0] + wscore[1] + wscore[2] + wscore[3]);
        atomicAdd(loss_sum, tot);
    }

    // ---- gather fp32 codebook rows -> output (coalesced float4) ----
    const float4* cb4  = (const float4*)cb;
    float4*       out4 = (float4*)out + (size_t)blockIdx.x * (BM * 64);
    #pragma unroll 4
    for (int i = 0; i < 64; i++) {
        int j = i * 256 + t;
        int r = j >> 6, c = j & 63;
        out4[j] = cb4[bestidx[r] * 64 + c];
    }
}

// ---------------- finalize: loss scalar + perplexity ----------------
__global__ __launch_bounds__(256) void vq_final(const unsigned int* __restrict__ counts,
                                                const float* __restrict__ loss_sum,
                                                float* __restrict__ outs) {
    __shared__ float red[4];
    int t = threadIdx.x, lane = t & 63, w = t >> 6;
    float h = 0.f;
    for (int i = t; i < NUM_EMB; i += 256) {
        float p = (float)counts[i] * (1.f / (float)N_ROWS);
        h += p * logf(p + 1e-10f);
    }
    #pragma unroll
    for (int off = 32; off; off >>= 1) h += __shfl_xor(h, off, 64);
    if (lane == 0) red[w] = h;
    __syncthreads();
    if (t == 0) {
        float H = red[0] + red[1] + red[2] + red[3];
        outs[0] = 1.25f * loss_sum[0] * (1.f / 67108864.f);  // loss = 1.25 * mean(dist_min)
        outs[1] = expf(-H);                                   // perplexity
    }
}

extern "C" void kernel_launch(void* const* d_in, const int* in_sizes, int n_in,
                              void* d_out, int out_size, void* d_ws, size_t ws_size,
                              hipStream_t stream) {
    (void)in_sizes; (void)n_in; (void)out_size; (void)ws_size;
    const float* in = (const float*)d_in[0];
    const float* cb = (const float*)d_in[1];
    float* out = (float*)d_out;

    char* ws = (char*)d_ws;
    __bf16*       cb_bf    = (__bf16*)(ws);                 // 1024*256*2 = 524288 B
    float*        cnorms   = (float*)(ws + 524288);         // 4096 B
    unsigned int* counts   = (unsigned int*)(ws + 528384);  // 4096 B
    float*        loss_sum = (float*)(ws + 532480);         // 4 B

    vq_prep<<<NUM_EMB, 64, 0, stream>>>(cb, cb_bf, cnorms, counts, loss_sum);
    vq_main<<<N_ROWS / BM, 256, 0, stream>>>(in, cb, cb_bf, cnorms, counts, loss_sum, out);
    vq_final<<<1, 256, 0, stream>>>(counts, loss_sum, out + 67108864);
}

// Round 2
// 668.384 us; speedup vs baseline: 1.3530x; 1.3530x over previous
//
#include <hip/hip_runtime.h>
#include <hip/hip_bf16.h>
#include <math.h>

#define NUM_EMB 1024
#define DIM 256
#define N_ROWS 262144            // 8*32*32*32
#define BM 128                   // rows per block (4 waves x 32 rows, mt=2)
#define NT_CODES 32              // codes per staged B tile
#define NG_ITERS (NUM_EMB / NT_CODES)

typedef __attribute__((ext_vector_type(8))) __bf16 bf16x8;
typedef __attribute__((ext_vector_type(4))) __bf16 bf16x4;
typedef __attribute__((ext_vector_type(4))) float  f32x4;

// direct global->LDS async copy, 16B per lane (lane-linear LDS dest: m104 caveat)
__device__ __forceinline__ void async_load16(const void* g, void* l) {
    __builtin_amdgcn_global_load_lds(
        (const __attribute__((address_space(1))) unsigned int*)g,
        (__attribute__((address_space(3))) unsigned int*)l, 16, 0, 0);
}

// ---------------- prep: codebook fp32 -> bf16, 0.5*||e||^2, zero counts/loss ----------------
__global__ __launch_bounds__(64) void vq_prep(const float* __restrict__ cb,
                                              __bf16* __restrict__ cb_bf,
                                              float* __restrict__ cnorms,
                                              unsigned int* __restrict__ counts,
                                              float* __restrict__ loss_sum) {
    int k = blockIdx.x, t = threadIdx.x;           // 1024 blocks x 64 threads, one code per block
    float4 v = ((const float4*)cb)[k * 64 + t];    // 64 threads x 4 floats = 256
    bf16x4 h = { (__bf16)v.x, (__bf16)v.y, (__bf16)v.z, (__bf16)v.w };
    ((bf16x4*)cb_bf)[k * 64 + t] = h;
    float ss = v.x * v.x + v.y * v.y + v.z * v.z + v.w * v.w;
    #pragma unroll
    for (int off = 32; off; off >>= 1) ss += __shfl_xor(ss, off, 64);
    if (t == 0) {
        cnorms[k] = 0.5f * ss;
        counts[k] = 0u;
        if (k == 0) loss_sum[0] = 0.f;
    }
}

// ---------------- main: fused GEMM-argmax + loss partials + histogram; idx -> ws ----------------
// LDS B tile is UNPADDED (global_load_lds needs lane-linear dest); bank conflicts broken by
// XOR swizzle: LDS granule (code c, pos p) holds global granule p^(c&7); read side applies same XOR.
__global__ __launch_bounds__(256, 3) void vq_main(const float* __restrict__ in,
                                                  const __bf16* __restrict__ cb_bf,
                                                  const float* __restrict__ cnorms,
                                                  unsigned int* __restrict__ counts,
                                                  float* __restrict__ loss_sum,
                                                  int* __restrict__ bidx_g) {
    __shared__ __bf16 Blds[2][NT_CODES * DIM];   // 2 x 16 KB
    __shared__ int    bestidx_s[BM];
    __shared__ float  bestscore_s[BM];
    __shared__ float  wsum[4], ssc[2];

    const int t    = threadIdx.x;
    const int lane = t & 63, w = t >> 6;
    const int col  = lane & 15, quad = lane >> 4;
    const int rowbase = blockIdx.x * BM + w * 32;

    // ---- A fragments: 32 rows x 256 d per wave, bf16 in registers (64 VGPRs) ----
    // A[m = lane&15][k = quad*8 + j]  (m120-verified layout), loaded direct from global fp32.
    bf16x8 afr[2][8];
    float sumsq = 0.f;
    const float4* in4 = (const float4*)in;
    #pragma unroll
    for (int mt = 0; mt < 2; mt++) {
        const float4* rp = in4 + (size_t)(rowbase + mt * 16 + col) * 64 + quad * 2;
        #pragma unroll
        for (int kk = 0; kk < 8; kk++) {
            float4 x0 = rp[kk * 8];
            float4 x1 = rp[kk * 8 + 1];
            sumsq += x0.x * x0.x + x0.y * x0.y + x0.z * x0.z + x0.w * x0.w
                   + x1.x * x1.x + x1.y * x1.y + x1.z * x1.z + x1.w * x1.w;
            bf16x8 a = { (__bf16)x0.x, (__bf16)x0.y, (__bf16)x0.z, (__bf16)x0.w,
                         (__bf16)x1.x, (__bf16)x1.y, (__bf16)x1.z, (__bf16)x1.w };
            afr[mt][kk] = a;
        }
    }

    float bs[2][4];
    int   bi[2][4];
    #pragma unroll
    for (int mt = 0; mt < 2; mt++)
        #pragma unroll
        for (int r = 0; r < 4; r++) { bs[mt][r] = -__builtin_inff(); bi[mt][r] = 0; }

    // ---- staging: 32 codes x 512B via global_load_lds, XOR-swizzled source granules ----
    auto stage = [&](int ng, int buf) {
        const char* src = (const char*)(cb_bf + (size_t)ng * NT_CODES * DIM);
        #pragma unroll
        for (int i = 0; i < 4; i++) {
            int G = i * 256 + t;                  // granule slot in tile (1024 x 16B)
            int c = G >> 5, gp = G & 31;
            int gs = gp ^ (c & 7);                // source granule for this LDS slot
            async_load16(src + (size_t)c * 512 + gs * 16, (char*)&Blds[buf][0] + (size_t)G * 16);
        }
    };

    stage(0, 0);
    __syncthreads();

    for (int ng = 0; ng < NG_ITERS; ng++) {
        int buf = ng & 1;
        // per-lane code norms for this tile (L1/L2-resident 4 KB) — issue early
        float cn0 = cnorms[ng * NT_CODES + col];
        float cn1 = cnorms[ng * NT_CODES + 16 + col];
        if (ng + 1 < NG_ITERS) stage(ng + 1, buf ^ 1);

        f32x4 acc[2][2];
        #pragma unroll
        for (int mt = 0; mt < 2; mt++) {
            f32x4 z = { 0.f, 0.f, 0.f, 0.f };
            acc[mt][0] = z;
            acc[mt][1] = z;
        }
        const __bf16* bp = &Blds[buf][0];
        #pragma unroll
        for (int kk = 0; kk < 8; kk++) {
            int gp0 = (4 * kk + quad) ^ (col & 7);          // swizzled granule pos
            bf16x8 b0 = *(const bf16x8*)(bp + col * DIM + gp0 * 8);
            bf16x8 b1 = *(const bf16x8*)(bp + (col + 16) * DIM + gp0 * 8);
            #pragma unroll
            for (int mt = 0; mt < 2; mt++) {
                acc[mt][0] = __builtin_amdgcn_mfma_f32_16x16x32_bf16(afr[mt][kk], b0, acc[mt][0], 0, 0, 0);
                acc[mt][1] = __builtin_amdgcn_mfma_f32_16x16x32_bf16(afr[mt][kk], b1, acc[mt][1], 0, 0, 0);
            }
        }
        // running argmax of s = x.e - 0.5||e||^2; C layout: col=lane&15, row=quad*4+reg (m89)
        int cb0 = ng * NT_CODES + col, cb1 = cb0 + 16;
        #pragma unroll
        for (int mt = 0; mt < 2; mt++) {
            #pragma unroll
            for (int r = 0; r < 4; r++) {
                float s0 = acc[mt][0][r] - cn0;
                if (s0 > bs[mt][r]) { bs[mt][r] = s0; bi[mt][r] = cb0; }
                float s1 = acc[mt][1][r] - cn1;
                if (s1 > bs[mt][r]) { bs[mt][r] = s1; bi[mt][r] = cb1; }
            }
        }
        __syncthreads();
    }

    // ---- cross-lane argmax over the 16 col-lanes sharing each row ----
    #pragma unroll
    for (int mt = 0; mt < 2; mt++) {
        #pragma unroll
        for (int r = 0; r < 4; r++) {
            float s = bs[mt][r];
            int   i = bi[mt][r];
            #pragma unroll
            for (int off = 1; off < 16; off <<= 1) {
                float so = __shfl_xor(s, off, 64);
                int   io = __shfl_xor(i, off, 64);
                if (so > s || (so == s && io < i)) { s = so; i = io; }
            }
            if (col == 0) {
                int rl = w * 32 + mt * 16 + quad * 4 + r;
                bestidx_s[rl]   = i;
                bestscore_s[rl] = s;
                bidx_g[blockIdx.x * BM + rl] = i;
            }
        }
    }

    // per-wave sum of x^2 (for loss)
    float v = sumsq;
    #pragma unroll
    for (int off = 32; off; off >>= 1) v += __shfl_xor(v, off, 64);
    if (lane == 0) wsum[w] = v;
    __syncthreads();

    if (t < BM) atomicAdd(&counts[bestidx_s[t]], 1u);

    // block loss partial: sum_x2 - 2 * sum(best score)
    if (w < 2) {
        float sc = bestscore_s[t];
        #pragma unroll
        for (int off = 32; off; off >>= 1) sc += __shfl_xor(sc, off, 64);
        if (lane == 0) ssc[w] = sc;
    }
    __syncthreads();
    if (t == 0) {
        float tot = (wsum[0] + wsum[1] + wsum[2] + wsum[3]) - 2.f * (ssc[0] + ssc[1]);
        atomicAdd(loss_sum, tot);
    }
}

// ---------------- gather: out[r,:] = cb[idx[r],:] (pure streaming write) ----------------
__global__ __launch_bounds__(256) void vq_gather(const float* __restrict__ cb,
                                                 const int* __restrict__ bidx,
                                                 float* __restrict__ out) {
    __shared__ int idx[64];
    const int b = blockIdx.x, t = threadIdx.x;
    if (t < 64) idx[t] = bidx[b * 64 + t];
    __syncthreads();
    const float4* cb4  = (const float4*)cb;
    float4*       out4 = (float4*)out + (size_t)b * 4096;   // 64 rows x 64 float4
    #pragma unroll
    for (int i = 0; i < 16; i++) {
        int j = i * 256 + t;
        int r = j >> 6, c = j & 63;
        out4[j] = cb4[idx[r] * 64 + c];
    }
}

// ---------------- finalize: loss scalar + perplexity ----------------
__global__ __launch_bounds__(256) void vq_final(const unsigned int* __restrict__ counts,
                                                const float* __restrict__ loss_sum,
                                                float* __restrict__ outs) {
    __shared__ float red[4];
    int t = threadIdx.x, lane = t & 63, w = t >> 6;
    float h = 0.f;
    for (int i = t; i < NUM_EMB; i += 256) {
        float p = (float)counts[i] * (1.f / (float)N_ROWS);
        h += p * logf(p + 1e-10f);
    }
    #pragma unroll
    for (int off = 32; off; off >>= 1) h += __shfl_xor(h, off, 64);
    if (lane == 0) red[w] = h;
    __syncthreads();
    if (t == 0) {
        float H = red[0] + red[1] + red[2] + red[3];
        outs[0] = 1.25f * loss_sum[0] * (1.f / 67108864.f);  // loss = 1.25 * mean(dist_min)
        outs[1] = expf(-H);                                   // perplexity
    }
}

extern "C" void kernel_launch(void* const* d_in, const int* in_sizes, int n_in,
                              void* d_out, int out_size, void* d_ws, size_t ws_size,
                              hipStream_t stream) {
    (void)in_sizes; (void)n_in; (void)out_size; (void)ws_size;
    const float* in = (const float*)d_in[0];
    const float* cb = (const float*)d_in[1];
    float* out = (float*)d_out;

    char* ws = (char*)d_ws;
    __bf16*       cb_bf    = (__bf16*)(ws);                 // 524288 B
    float*        cnorms   = (float*)(ws + 524288);         // 4096 B
    unsigned int* counts   = (unsigned int*)(ws + 528384);  // 4096 B
    float*        loss_sum = (float*)(ws + 532480);         // 4 B (pad to 256)
    int*          bidx     = (int*)(ws + 532736);           // 1 MB

    vq_prep<<<NUM_EMB, 64, 0, stream>>>(cb, cb_bf, cnorms, counts, loss_sum);
    vq_main<<<N_ROWS / BM, 256, 0, stream>>>(in, cb_bf, cnorms, counts, loss_sum, bidx);
    vq_gather<<<N_ROWS / 64, 256, 0, stream>>>(cb, bidx, out);
    vq_final<<<1, 256, 0, stream>>>(counts, loss_sum, out + 67108864);
}